// Round 6
// baseline (335.360 us; speedup 1.0000x reference)
//
#include <hip/hip_runtime.h>
#include <math.h>

#define BATCH 1024
#define VOCAB 100000
#define KDIM  300
#define TOPK  10

#define NKB    10            // K blocks of 32 (K padded 300 -> 320)
#define NCB_B  6272          // vocab col-blocks of 16 (98 chunks * 64), pad to 100352
#define NCB_A  64            // 1024 rows / 16
#define NCHUNK 98            // col chunks of 1024
#define NWIN   8             // 128-col windows per chunk
#define NSTEP  (NWIN*NKB)    // 80 pipeline steps per block
#define CSLOT  32            // candidate u32s per (row, chunk): 2 wn * 4 lk * depth 4
#define NCAND  (NCHUNK*CSLOT) // 3136 per row (quad candidates)
#define NKF    24            // final quad rescore set -> 96 cols

typedef __attribute__((ext_vector_type(8))) short bf16x8;
typedef __attribute__((ext_vector_type(4))) float f32x4;

#define GL2LDS(gsrc, ldst)                                                    \
    __builtin_amdgcn_global_load_lds(                                         \
        (const __attribute__((address_space(1))) void*)(gsrc),                \
        (__attribute__((address_space(3))) void*)(ldst), 16, 0, 0)

__device__ __forceinline__ ushort f2bf(float f) {
    union { float f; unsigned u; } v; v.f = f;
    unsigned r = v.u + 0x7FFFu + ((v.u >> 16) & 1u);  // RNE
    return (ushort)(r >> 16);
}

// depth-4 descending insert, SIGNED keys (sentinel 0; negatives never insert)
__device__ __forceinline__ void ins4(int (&l)[4], int e) {
    if (e <= l[3]) return;
    bool g0 = e > l[0], g1 = e > l[1], g2 = e > l[2];
    l[3] = g2 ? l[2] : e;
    l[2] = g2 ? (g1 ? l[1] : e) : l[2];
    l[1] = g1 ? (g0 ? l[0] : e) : l[1];
    l[0] = g0 ? e : l[0];
}

// descending (key,val) insert, depth N, SIGNED keys, fully unrolled
template<int N>
__device__ __forceinline__ void pins(int (&ks)[N], int (&vs)[N], int k, int v) {
    if (k <= ks[N-1]) return;
    #pragma unroll
    for (int p = N-1; p >= 0; --p) {
        bool gt  = k > ks[p];
        bool gtp = (p > 0) ? (k > ks[p-1]) : false;
        int nk = gt ? (gtp ? ks[p-1] : k) : ks[p];
        int nv = gt ? (gtp ? vs[p-1] : v) : vs[p];
        ks[p] = nk; vs[p] = nv;
    }
}

// ---------------------------------------------------------------------------
// Kernel 1: pack weight (and gathered query rows) into bf16 MFMA fragments,
// kb-OUTER layout (4 col-blocks per workgroup):
//   B frag (kb, cb):   ws_b[((kb*NCB_B + cb)*64 + lane)*8 .. +7]
//   A frag (kb, rb16): ws_a[((kb*64   + rb16)*64 + lane)*8 .. +7]
// Fragment: elem (idx16 = lane&15, k = kb*32 + (lane>>4)*8 + j)  [r2-verified]
// ---------------------------------------------------------------------------
__global__ __launch_bounds__(256)
void convert_frags(const int* __restrict__ wordid, const float* __restrict__ weight,
                   ushort* __restrict__ ws_b, ushort* __restrict__ ws_a, int nb4)
{
    __shared__ float Raw[16][324];
    __shared__ int   Rows[16];

    const int bid = blockIdx.x;
    const int t   = threadIdx.x;
    const bool is_a = (bid >= nb4);
    const int cb0 = (is_a ? (bid - nb4) : bid) * 4;
    ushort* dst = is_a ? ws_a : ws_b;
    const int kstride = is_a ? 64 : NCB_B;

    for (int sub = 0; sub < 4; ++sub) {
        const int cb = cb0 + sub;
        __syncthreads();                      // protect Raw from prev iter readers
        if (t < 16) {
            int gr = is_a ? wordid[cb*16 + t] : (cb*16 + t);
            Rows[t] = (gr < VOCAB) ? gr : -1;
        }
        __syncthreads();
        // 16 rows x 80 float4 slots (=320 floats); slots 75..79 zero pad
        for (int idx = t; idx < 16*80; idx += 256) {
            int row = idx / 80;
            int f4  = idx - row*80;
            int gr  = Rows[row];
            float4 v = make_float4(0.f,0.f,0.f,0.f);
            if (gr >= 0 && f4 < 75)
                v = *reinterpret_cast<const float4*>(&weight[(size_t)gr*KDIM + f4*4]);
            *reinterpret_cast<float4*>(&Raw[row][f4*4]) = v;
        }
        __syncthreads();
        for (int idx = t; idx < NKB*64; idx += 256) {
            int kb   = idx >> 6;
            int lane = idx & 63;
            int r16  = lane & 15;
            int k0   = kb*32 + (lane>>4)*8;
            unsigned p[4];
            #pragma unroll
            for (int q = 0; q < 4; ++q) {
                unsigned lo = f2bf(Raw[r16][k0 + 2*q]);
                unsigned hi = f2bf(Raw[r16][k0 + 2*q + 1]);
                p[q] = lo | (hi << 16);
            }
            *reinterpret_cast<uint4*>(&dst[((size_t)kb*kstride + cb)*512 + (size_t)lane*8]) =
                make_uint4(p[0], p[1], p[2], p[3]);
        }
    }
}

// ---------------------------------------------------------------------------
// Kernel 2: counted-vmcnt 3-buffer MFMA pipeline (swapped operands) + fused
// per-row quad-max top-4 candidate lists (signed packed keys).
// Block: 256 thr / 4 waves (2x2); block tile 128 rows x 128 cols per window;
// grid (8 rowblocks, 98 chunks) so consecutive blocks share the B panel.
// Step s = it*NKB+kb: read buf[s%3], batch s+1 landing, stage s+2 -> (s+2)%3.
// Per step per wave: 4 GL2LDS issues -> steady-state wait vmcnt(4).
// ---------------------------------------------------------------------------
__global__ __launch_bounds__(256, 3)
void sim_gemm(const ushort* __restrict__ ws_a, const ushort* __restrict__ ws_b,
              unsigned* __restrict__ cand)
{
    __shared__ __align__(16) ushort Abuf[3][8*512];   // 3 x 8 KB
    __shared__ __align__(16) ushort Bbuf[3][8*512];

    const int t     = threadIdx.x;
    const int wid   = t >> 6, lane = t & 63;
    const int wm    = wid >> 1, wn = wid & 1;
    const int l16   = lane & 15, lk = lane >> 4;
    const int rb16b = blockIdx.x * 8;    // rowblock16 base of this block
    const int chunk = blockIdx.y;        // 0..97

    int ps[4][4];
    #pragma unroll
    for (int m = 0; m < 4; ++m)
        #pragma unroll
        for (int e = 0; e < 4; ++e) ps[m][e] = 0;

    const int f = wid * 2;               // this wave's 2 frag slots
    const ushort* abase = ws_a + ((size_t)(rb16b + f)*512) + (size_t)lane*8;
    const ushort* bbase = ws_b + ((size_t)(chunk*64 + f)*512) + (size_t)lane*8;

    auto stage = [&](int sit, int skb, int buf) {
        const ushort* pa = abase + (size_t)skb*(64*512);
        GL2LDS(pa,       &Abuf[buf][f*512]);
        GL2LDS(pa + 512, &Abuf[buf][(f+1)*512]);
        const ushort* pb = bbase + (size_t)skb*((size_t)NCB_B*512) + (size_t)sit*(8*512);
        GL2LDS(pb,       &Bbuf[buf][f*512]);
        GL2LDS(pb + 512, &Bbuf[buf][(f+1)*512]);
    };

    stage(0, 0, 0);
    stage(0, 1, 1);
    int nit = 0, nkb = 2;                // next batch (it,kb) to stage
    int cur = 0;                         // s % 3
    int s = 0;
    const int qbase = wn*16 + lk;        // quad id: it*32 + n*4 + qbase

    for (int it = 0; it < NWIN; ++it) {
        f32x4 acc[4][4] = {};

        for (int kb = 0; kb < NKB; ++kb, ++s) {
            if (s == NSTEP-1) { asm volatile("s_waitcnt vmcnt(0)" ::: "memory"); }
            else              { asm volatile("s_waitcnt vmcnt(4)" ::: "memory"); }
            __builtin_amdgcn_s_barrier();
            asm volatile("" ::: "memory");

            bf16x8 af[4], bfr[4];
            #pragma unroll
            for (int m = 0; m < 4; ++m)
                af[m] = *reinterpret_cast<const bf16x8*>(&Abuf[cur][(wm*4+m)*512 + lane*8]);
            #pragma unroll
            for (int n = 0; n < 4; ++n)
                bfr[n] = *reinterpret_cast<const bf16x8*>(&Bbuf[cur][(wn*4+n)*512 + lane*8]);

            if (s < NSTEP-2) {
                int nxt = cur - 1; if (nxt < 0) nxt = 2;   // (s+2)%3
                stage(nit, nkb, nxt);
                ++nkb; if (nkb == NKB) { nkb = 0; ++nit; }
            }

            #pragma unroll
            for (int m = 0; m < 4; ++m)
                #pragma unroll
                for (int n = 0; n < 4; ++n)
                    acc[m][n] = __builtin_amdgcn_mfma_f32_16x16x32_bf16(bfr[n], af[m], acc[m][n], 0, 0, 0);

            ++cur; if (cur == 3) cur = 0;
        }

        // quad scan: one insert per (m,n) quad of 4 consecutive cols
        #pragma unroll
        for (int m = 0; m < 4; ++m)
            #pragma unroll
            for (int n = 0; n < 4; ++n) {
                float qm = fmaxf(fmaxf(acc[m][n][0], acc[m][n][1]),
                                 fmaxf(acc[m][n][2], acc[m][n][3]));
                int key = (int)((__float_as_uint(qm) & 0xFFFF0000u)
                                | (unsigned)(it*32 + n*4 + qbase));
                ins4(ps[m], key);
            }
    }

    // writeout: cand[row][chunk][wn][lk][4] as uint4
    #pragma unroll
    for (int m = 0; m < 4; ++m) {
        int row = rb16b*16 + wm*64 + m*16 + l16;
        size_t base = (size_t)row*NCAND + chunk*CSLOT + wn*16 + lk*4;
        *reinterpret_cast<uint4*>(&cand[base]) =
            make_uint4((unsigned)ps[m][0], (unsigned)ps[m][1],
                       (unsigned)ps[m][2], (unsigned)ps[m][3]);
    }
}

// ---------------------------------------------------------------------------
// Kernel 3: per row, merge 3136 quad candidates -> top-24 quads by approx key,
// exact fp64 rescore of all 96 cols, top-11 with numpy tie-break, drop rank-1.
// ---------------------------------------------------------------------------
__global__ __launch_bounds__(128, 4)
void merge_rescore(const unsigned* __restrict__ cand, const int* __restrict__ wordid,
                   const float* __restrict__ weight, float* __restrict__ out)
{
    __shared__ int    Ks[128*8];
    __shared__ int    Vs[128*8];
    __shared__ int    Fq[NKF];
    __shared__ double Rs[NKF*4];
    __shared__ int    Rc[NKF*4];

    const int row  = blockIdx.x;
    const int lane = threadIdx.x;   // 0..127

    int ks[8]; int vs[8];
    #pragma unroll
    for (int i = 0; i < 8; ++i) { ks[i] = 0; vs[i] = 0; }

    const unsigned* rc = cand + (size_t)row*NCAND;
    for (int c = lane; c < NCAND; c += 128) {
        int e  = (int)rc[c];
        int gq = ((c >> 5) << 8) | (e & 255);   // chunk*256 + local quad
        pins<8>(ks, vs, e, gq);
    }
    #pragma unroll
    for (int i = 0; i < 8; ++i) { Ks[lane*8 + i] = ks[i]; Vs[lane*8 + i] = vs[i]; }
    __syncthreads();

    if (lane == 0) {
        int gk[NKF]; int gv[NKF];
        #pragma unroll
        for (int i = 0; i < NKF; ++i) { gk[i] = 0; gv[i] = 0; }
        for (int l = 0; l < 128; ++l) {
            for (int i = 0; i < 8; ++i) {         // lane lists sorted desc
                int e = Ks[l*8 + i];
                if (e <= gk[NKF-1]) break;
                pins<NKF>(gk, gv, e, Vs[l*8 + i]);
            }
        }
        #pragma unroll
        for (int i = 0; i < NKF; ++i) Fq[i] = gv[i];
    }
    __syncthreads();

    if (lane < NKF*4) {
        int q   = Fq[lane >> 2];
        int col = q*4 + (lane & 3);
        double s = -1e300;
        if (col < VOCAB) {
            const float4* q4 = reinterpret_cast<const float4*>(weight + (size_t)wordid[row]*KDIM);
            const float4* w4 = reinterpret_cast<const float4*>(weight + (size_t)col*KDIM);
            double a0=0, a1=0, a2=0, a3=0;
            #pragma unroll 5
            for (int i = 0; i < 75; ++i) {
                float4 a = q4[i], b = w4[i];
                a0 += (double)a.x * b.x; a1 += (double)a.y * b.y;
                a2 += (double)a.z * b.z; a3 += (double)a.w * b.w;
            }
            s = (a0 + a1) + (a2 + a3);
        }
        Rs[lane] = s; Rc[lane] = col;
    }
    __syncthreads();

    if (lane == 0) {
        unsigned long long used = 0ull;
        for (int kk = 0; kk < TOPK + 1; ++kk) {
            int best = -1; double bs = -1e300; int bi = 0x7fffffff;
            for (int i = 0; i < NKF*4; ++i) {
                if ((used >> i) & 1ull) continue;
                double sc = Rs[i]; int vv = Rc[i];
                if (sc > bs || (sc == bs && vv < bi)) { best = i; bs = sc; bi = vv; }
            }
            used |= 1ull << best;
            if (kk >= 1) {
                out[(size_t)row*TOPK + (kk-1)] = (float)bs;
                out[(size_t)BATCH*TOPK + (size_t)row*TOPK + (kk-1)] = (float)bi;
            }
        }
    }
}

extern "C" void kernel_launch(void* const* d_in, const int* in_sizes, int n_in,
                              void* d_out, int out_size, void* d_ws, size_t ws_size,
                              hipStream_t stream) {
    const int*   wordid = (const int*)d_in[0];
    const float* weight = (const float*)d_in[1];
    float* out = (float*)d_out;

    const size_t SZ_B = (size_t)NCB_B * NKB * 64 * 16;   // 64,225,280 B
    const size_t SZ_A = (size_t)NCB_A * NKB * 64 * 16;   //    655,360 B
    // cand: 1024 * 3136 * 4 = 12,845,056 B ; total ~77.7 MB (fits, per round 5)

    char* p = (char*)d_ws;
    ushort*   ws_b = (ushort*)p;  p += SZ_B;
    ushort*   ws_a = (ushort*)p;  p += SZ_A;
    unsigned* cand = (unsigned*)p;

    convert_frags<<<NCB_B/4 + NCB_A/4, 256, 0, stream>>>(wordid, weight, ws_b, ws_a, NCB_B/4);
    sim_gemm<<<dim3(8, NCHUNK), 256, 0, stream>>>(ws_a, ws_b, cand);
    merge_rescore<<<BATCH, 128, 0, stream>>>(cand, wordid, weight, out);
}

// Round 7
// 270.314 us; speedup vs baseline: 1.2406x; 1.2406x over previous
//
#include <hip/hip_runtime.h>
#include <math.h>

#define BATCH 1024
#define VOCAB 100000
#define KDIM  300
#define TOPK  10

#define NKB    10            // K blocks of 32 (K padded 300 -> 320)
#define NCB_B  6272          // vocab col-blocks of 16 (98 chunks * 64), pad to 100352
#define NCB_A  64            // 1024 rows / 16
#define NCHUNK 98            // col chunks of 1024
#define NWIN   8             // 128-col windows per chunk
#define NSTEP  (NWIN*NKB)    // 80 pipeline steps per block
#define CSLOT  32            // candidate u32s per (row, chunk): 2 wn * 4 lk * depth 4
#define NCAND  (NCHUNK*CSLOT) // 3136 per row (quad candidates)
#define NKF    24            // final quad rescore set -> 96 cols
#define NDOT   (NKF*4)       // 96 exact dots per row

typedef __attribute__((ext_vector_type(8))) short bf16x8;
typedef __attribute__((ext_vector_type(4))) float f32x4;

#define GL2LDS(gsrc, ldst)                                                    \
    __builtin_amdgcn_global_load_lds(                                         \
        (const __attribute__((address_space(1))) void*)(gsrc),                \
        (__attribute__((address_space(3))) void*)(ldst), 16, 0, 0)

__device__ __forceinline__ ushort f2bf(float f) {
    union { float f; unsigned u; } v; v.f = f;
    unsigned r = v.u + 0x7FFFu + ((v.u >> 16) & 1u);  // RNE
    return (ushort)(r >> 16);
}

// depth-4 descending insert, SIGNED keys (sentinel 0; negatives never insert)
__device__ __forceinline__ void ins4(int (&l)[4], int e) {
    if (e <= l[3]) return;
    bool g0 = e > l[0], g1 = e > l[1], g2 = e > l[2];
    l[3] = g2 ? l[2] : e;
    l[2] = g2 ? (g1 ? l[1] : e) : l[2];
    l[1] = g1 ? (g0 ? l[0] : e) : l[1];
    l[0] = g0 ? e : l[0];
}

// descending (key,val) insert, depth N, SIGNED keys, fully unrolled
template<int N>
__device__ __forceinline__ void pins(int (&ks)[N], int (&vs)[N], int k, int v) {
    if (k <= ks[N-1]) return;
    #pragma unroll
    for (int p = N-1; p >= 0; --p) {
        bool gt  = k > ks[p];
        bool gtp = (p > 0) ? (k > ks[p-1]) : false;
        int nk = gt ? (gtp ? ks[p-1] : k) : ks[p];
        int nv = gt ? (gtp ? vs[p-1] : v) : vs[p];
        ks[p] = nk; vs[p] = nv;
    }
}

// ---------------------------------------------------------------------------
// Kernel 1: pack weight (and gathered query rows) into bf16 MFMA fragments,
// kb-OUTER layout (4 col-blocks per workgroup).  [unchanged from round 6]
// ---------------------------------------------------------------------------
__global__ __launch_bounds__(256)
void convert_frags(const int* __restrict__ wordid, const float* __restrict__ weight,
                   ushort* __restrict__ ws_b, ushort* __restrict__ ws_a, int nb4)
{
    __shared__ float Raw[16][324];
    __shared__ int   Rows[16];

    const int bid = blockIdx.x;
    const int t   = threadIdx.x;
    const bool is_a = (bid >= nb4);
    const int cb0 = (is_a ? (bid - nb4) : bid) * 4;
    ushort* dst = is_a ? ws_a : ws_b;
    const int kstride = is_a ? 64 : NCB_B;

    for (int sub = 0; sub < 4; ++sub) {
        const int cb = cb0 + sub;
        __syncthreads();                      // protect Raw from prev iter readers
        if (t < 16) {
            int gr = is_a ? wordid[cb*16 + t] : (cb*16 + t);
            Rows[t] = (gr < VOCAB) ? gr : -1;
        }
        __syncthreads();
        for (int idx = t; idx < 16*80; idx += 256) {
            int row = idx / 80;
            int f4  = idx - row*80;
            int gr  = Rows[row];
            float4 v = make_float4(0.f,0.f,0.f,0.f);
            if (gr >= 0 && f4 < 75)
                v = *reinterpret_cast<const float4*>(&weight[(size_t)gr*KDIM + f4*4]);
            *reinterpret_cast<float4*>(&Raw[row][f4*4]) = v;
        }
        __syncthreads();
        for (int idx = t; idx < NKB*64; idx += 256) {
            int kb   = idx >> 6;
            int lane = idx & 63;
            int r16  = lane & 15;
            int k0   = kb*32 + (lane>>4)*8;
            unsigned p[4];
            #pragma unroll
            for (int q = 0; q < 4; ++q) {
                unsigned lo = f2bf(Raw[r16][k0 + 2*q]);
                unsigned hi = f2bf(Raw[r16][k0 + 2*q + 1]);
                p[q] = lo | (hi << 16);
            }
            *reinterpret_cast<uint4*>(&dst[((size_t)kb*kstride + cb)*512 + (size_t)lane*8]) =
                make_uint4(p[0], p[1], p[2], p[3]);
        }
    }
}

// ---------------------------------------------------------------------------
// Kernel 2: counted-vmcnt 3-buffer MFMA pipeline + fused quad-max candidates.
// [unchanged from round 6]
// ---------------------------------------------------------------------------
__global__ __launch_bounds__(256, 3)
void sim_gemm(const ushort* __restrict__ ws_a, const ushort* __restrict__ ws_b,
              unsigned* __restrict__ cand)
{
    __shared__ __align__(16) ushort Abuf[3][8*512];
    __shared__ __align__(16) ushort Bbuf[3][8*512];

    const int t     = threadIdx.x;
    const int wid   = t >> 6, lane = t & 63;
    const int wm    = wid >> 1, wn = wid & 1;
    const int l16   = lane & 15, lk = lane >> 4;
    const int rb16b = blockIdx.x * 8;
    const int chunk = blockIdx.y;

    int ps[4][4];
    #pragma unroll
    for (int m = 0; m < 4; ++m)
        #pragma unroll
        for (int e = 0; e < 4; ++e) ps[m][e] = 0;

    const int f = wid * 2;
    const ushort* abase = ws_a + ((size_t)(rb16b + f)*512) + (size_t)lane*8;
    const ushort* bbase = ws_b + ((size_t)(chunk*64 + f)*512) + (size_t)lane*8;

    auto stage = [&](int sit, int skb, int buf) {
        const ushort* pa = abase + (size_t)skb*(64*512);
        GL2LDS(pa,       &Abuf[buf][f*512]);
        GL2LDS(pa + 512, &Abuf[buf][(f+1)*512]);
        const ushort* pb = bbase + (size_t)skb*((size_t)NCB_B*512) + (size_t)sit*(8*512);
        GL2LDS(pb,       &Bbuf[buf][f*512]);
        GL2LDS(pb + 512, &Bbuf[buf][(f+1)*512]);
    };

    stage(0, 0, 0);
    stage(0, 1, 1);
    int nit = 0, nkb = 2;
    int cur = 0;
    int s = 0;
    const int qbase = wn*16 + lk;

    for (int it = 0; it < NWIN; ++it) {
        f32x4 acc[4][4] = {};

        for (int kb = 0; kb < NKB; ++kb, ++s) {
            if (s == NSTEP-1) { asm volatile("s_waitcnt vmcnt(0)" ::: "memory"); }
            else              { asm volatile("s_waitcnt vmcnt(4)" ::: "memory"); }
            __builtin_amdgcn_s_barrier();
            asm volatile("" ::: "memory");

            bf16x8 af[4], bfr[4];
            #pragma unroll
            for (int m = 0; m < 4; ++m)
                af[m] = *reinterpret_cast<const bf16x8*>(&Abuf[cur][(wm*4+m)*512 + lane*8]);
            #pragma unroll
            for (int n = 0; n < 4; ++n)
                bfr[n] = *reinterpret_cast<const bf16x8*>(&Bbuf[cur][(wn*4+n)*512 + lane*8]);

            if (s < NSTEP-2) {
                int nxt = cur - 1; if (nxt < 0) nxt = 2;
                stage(nit, nkb, nxt);
                ++nkb; if (nkb == NKB) { nkb = 0; ++nit; }
            }

            #pragma unroll
            for (int m = 0; m < 4; ++m)
                #pragma unroll
                for (int n = 0; n < 4; ++n)
                    acc[m][n] = __builtin_amdgcn_mfma_f32_16x16x32_bf16(bfr[n], af[m], acc[m][n], 0, 0, 0);

            ++cur; if (cur == 3) cur = 0;
        }

        #pragma unroll
        for (int m = 0; m < 4; ++m)
            #pragma unroll
            for (int n = 0; n < 4; ++n) {
                float qm = fmaxf(fmaxf(acc[m][n][0], acc[m][n][1]),
                                 fmaxf(acc[m][n][2], acc[m][n][3]));
                int key = (int)((__float_as_uint(qm) & 0xFFFF0000u)
                                | (unsigned)(it*32 + n*4 + qbase));
                ins4(ps[m], key);
            }
    }

    #pragma unroll
    for (int m = 0; m < 4; ++m) {
        int row = rb16b*16 + wm*64 + m*16 + l16;
        size_t base = (size_t)row*NCAND + chunk*CSLOT + wn*16 + lk*4;
        *reinterpret_cast<uint4*>(&cand[base]) =
            make_uint4((unsigned)ps[m][0], (unsigned)ps[m][1],
                       (unsigned)ps[m][2], (unsigned)ps[m][3]);
    }
}

// ---------------------------------------------------------------------------
// Kernel 3a: per row, hierarchical merge 3136 quad candidates -> top-24 quads.
// 128 lanes gather depth-8 -> 16 lanes merge 8 lists each -> lane 0 merges 16.
// (Each chunk's 32 slots map to 32 distinct lanes -> a lane holds >8 of the
// global top-24 with probability ~1e-12.)
// ---------------------------------------------------------------------------
__global__ __launch_bounds__(128, 4)
void merge_topq(const unsigned* __restrict__ cand, int* __restrict__ quads)
{
    __shared__ int Ks[128*8];
    __shared__ int Vs[128*8];
    __shared__ int K24[16*NKF];
    __shared__ int V24[16*NKF];

    const int row  = blockIdx.x;
    const int lane = threadIdx.x;

    int ks[8]; int vs[8];
    #pragma unroll
    for (int i = 0; i < 8; ++i) { ks[i] = 0; vs[i] = 0; }

    const unsigned* rc = cand + (size_t)row*NCAND;
    for (int c = lane; c < NCAND; c += 128) {
        int e  = (int)rc[c];
        int gq = ((c >> 5) << 8) | (e & 255);   // chunk*256 + local quad
        pins<8>(ks, vs, e, gq);
    }
    #pragma unroll
    for (int i = 0; i < 8; ++i) { Ks[lane*8 + i] = ks[i]; Vs[lane*8 + i] = vs[i]; }
    __syncthreads();

    if (lane < 16) {
        int gk[NKF]; int gv[NKF];
        #pragma unroll
        for (int i = 0; i < NKF; ++i) { gk[i] = 0; gv[i] = 0; }
        for (int l = lane*8; l < lane*8 + 8; ++l) {
            for (int i = 0; i < 8; ++i) {          // lane lists sorted desc
                int e = Ks[l*8 + i];
                if (e <= gk[NKF-1]) break;
                pins<NKF>(gk, gv, e, Vs[l*8 + i]);
            }
        }
        #pragma unroll
        for (int i = 0; i < NKF; ++i) { K24[lane*NKF + i] = gk[i]; V24[lane*NKF + i] = gv[i]; }
    }
    __syncthreads();

    if (lane == 0) {
        int gk[NKF]; int gv[NKF];
        #pragma unroll
        for (int i = 0; i < NKF; ++i) { gk[i] = 0; gv[i] = 0; }
        for (int l = 0; l < 16; ++l) {
            for (int i = 0; i < NKF; ++i) {
                int e = K24[l*NKF + i];
                if (e <= gk[NKF-1]) break;
                pins<NKF>(gk, gv, e, V24[l*NKF + i]);
            }
        }
        #pragma unroll
        for (int i = 0; i < NKF; ++i) quads[row*NKF + i] = gv[i];
    }
}

// ---------------------------------------------------------------------------
// Kernel 3b: dense exact rescore. One 16-lane group per dot; 98304 dots.
// fp64 accumulate, shfl_xor reduce within group; scores[g] as double.
// ---------------------------------------------------------------------------
__global__ __launch_bounds__(256, 8)
void rescore_exact(const int* __restrict__ quads, const int* __restrict__ wordid,
                   const float* __restrict__ weight, double* __restrict__ scores)
{
    const int g = (blockIdx.x * 256 + threadIdx.x) >> 4;   // dot id
    const int l = threadIdx.x & 15;
    const int row = g / NDOT;
    const int ci  = g - row * NDOT;

    const int q   = quads[row*NKF + (ci >> 2)];
    const int col = q*4 + (ci & 3);
    const bool valid = (col < VOCAB);
    const int col_eff = valid ? col : 0;

    const float* qr = weight + (size_t)wordid[row]*KDIM;
    const float* wr = weight + (size_t)col_eff*KDIM;

    double a0 = 0.0, a1 = 0.0;
    #pragma unroll
    for (int k = 0; k < 4; ++k) {
        int sl = (l + 16*k) * 4;
        float4 qa = *reinterpret_cast<const float4*>(qr + sl);
        float4 wb = *reinterpret_cast<const float4*>(wr + sl);
        a0 += (double)qa.x * wb.x + (double)qa.z * wb.z;
        a1 += (double)qa.y * wb.y + (double)qa.w * wb.w;
    }
    if (l < 11) {
        int sl = (l + 64) * 4;
        float4 qa = *reinterpret_cast<const float4*>(qr + sl);
        float4 wb = *reinterpret_cast<const float4*>(wr + sl);
        a0 += (double)qa.x * wb.x + (double)qa.z * wb.z;
        a1 += (double)qa.y * wb.y + (double)qa.w * wb.w;
    }
    double a = a0 + a1;
    #pragma unroll
    for (int m = 1; m < 16; m <<= 1) a += __shfl_xor(a, m);

    if (l == 0) scores[g] = valid ? a : -1e300;
}

// ---------------------------------------------------------------------------
// Kernel 3c: per row, wave-parallel top-11 of the 96 exact scores
// (11 rounds of 64-lane shfl argmax, numpy tie-break: lower col wins),
// drop rank-1, write 10 scores + 10 indices (as float).
// ---------------------------------------------------------------------------
__global__ __launch_bounds__(64, 8)
void final_select(const double* __restrict__ scores, const int* __restrict__ quads,
                  float* __restrict__ out)
{
    const int row  = blockIdx.x;
    const int lane = threadIdx.x;

    double v0 = -INFINITY, v1 = -INFINITY;
    int    c0 = 0x7fffffff, c1 = 0x7fffffff;
    if (lane < NDOT/2) {
        int i0 = lane*2, i1 = lane*2 + 1;
        v0 = scores[(size_t)row*NDOT + i0];
        v1 = scores[(size_t)row*NDOT + i1];
        c0 = quads[row*NKF + (i0 >> 2)]*4 + (i0 & 3);
        c1 = quads[row*NKF + (i1 >> 2)]*4 + (i1 & 3);
    }

    for (int kk = 0; kk < TOPK + 1; ++kk) {
        bool sel = (v0 > v1) || (v0 == v1 && c0 < c1);
        double bv = sel ? v0 : v1;
        int    bc = sel ? c0 : c1;
        #pragma unroll
        for (int m = 1; m < 64; m <<= 1) {
            double ov = __shfl_xor(bv, m);
            int    oc = __shfl_xor(bc, m);
            if (ov > bv || (ov == bv && oc < bc)) { bv = ov; bc = oc; }
        }
        if (kk >= 1 && lane == 0) {
            out[(size_t)row*TOPK + (kk-1)] = (float)bv;
            out[(size_t)BATCH*TOPK + (size_t)row*TOPK + (kk-1)] = (float)bc;
        }
        if (c0 == bc) v0 = -INFINITY;
        if (c1 == bc) v1 = -INFINITY;
    }
}

extern "C" void kernel_launch(void* const* d_in, const int* in_sizes, int n_in,
                              void* d_out, int out_size, void* d_ws, size_t ws_size,
                              hipStream_t stream) {
    const int*   wordid = (const int*)d_in[0];
    const float* weight = (const float*)d_in[1];
    float* out = (float*)d_out;

    const size_t SZ_B = (size_t)NCB_B * NKB * 64 * 16;   // 64,225,280 B
    const size_t SZ_A = (size_t)NCB_A * NKB * 64 * 16;   //    655,360 B
    // footprint identical to round 6 (77.7 MB): quads overlays dead ws_a,
    // scores overlays dead cand.

    char* p = (char*)d_ws;
    ushort*   ws_b = (ushort*)p;  p += SZ_B;
    ushort*   ws_a = (ushort*)p;  p += SZ_A;
    unsigned* cand = (unsigned*)p;

    int*    quads  = (int*)ws_a;      // ws_a dead after sim_gemm (needs 96 KB <= 640 KB)
    double* scores = (double*)cand;   // cand dead after merge_topq (786 KB <= 12.8 MB)

    convert_frags<<<NCB_B/4 + NCB_A/4, 256, 0, stream>>>(wordid, weight, ws_b, ws_a, NCB_B/4);
    sim_gemm<<<dim3(8, NCHUNK), 256, 0, stream>>>(ws_a, ws_b, cand);
    merge_topq<<<BATCH, 128, 0, stream>>>(cand, quads);
    rescore_exact<<<(BATCH*NDOT)/16, 256, 0, stream>>>(quads, wordid, weight, scores);
    final_select<<<BATCH, 64, 0, stream>>>(scores, quads, out);
}

// Round 8
// 259.522 us; speedup vs baseline: 1.2922x; 1.0416x over previous
//
#include <hip/hip_runtime.h>
#include <math.h>

#define BATCH 1024
#define VOCAB 100000
#define KDIM  300
#define TOPK  10

#define NKB    10            // K blocks of 32 (K padded 300 -> 320)
#define NCB_B  6272          // vocab col-blocks of 16 (98 chunks * 64), pad to 100352
#define NCB_A  64            // 1024 rows / 16
#define NCHUNK 98            // col chunks of 1024
#define NCHPAD 104           // padded to multiple of 8 for XCD swizzle
#define NWIN   8             // 128-col windows per chunk
#define NSTEP  (NWIN*NKB)    // 80 pipeline steps per block
#define CSLOT  32            // candidate u32s per (row, chunk): 2 wn * 4 lk * depth 4
#define NCAND  (NCHUNK*CSLOT) // 3136 per row (quad candidates)
#define NKF    24            // final quad rescore set -> 96 cols
#define NDOT   (NKF*4)       // 96 exact dots per row

typedef __attribute__((ext_vector_type(8))) short bf16x8;
typedef __attribute__((ext_vector_type(4))) float f32x4;

#define GL2LDS(gsrc, ldst)                                                    \
    __builtin_amdgcn_global_load_lds(                                         \
        (const __attribute__((address_space(1))) void*)(gsrc),                \
        (__attribute__((address_space(3))) void*)(ldst), 16, 0, 0)

__device__ __forceinline__ ushort f2bf(float f) {
    union { float f; unsigned u; } v; v.f = f;
    unsigned r = v.u + 0x7FFFu + ((v.u >> 16) & 1u);  // RNE
    return (ushort)(r >> 16);
}

// depth-4 descending insert, SIGNED keys (sentinel 0; negatives never insert)
__device__ __forceinline__ void ins4(int (&l)[4], int e) {
    if (e <= l[3]) return;
    bool g0 = e > l[0], g1 = e > l[1], g2 = e > l[2];
    l[3] = g2 ? l[2] : e;
    l[2] = g2 ? (g1 ? l[1] : e) : l[2];
    l[1] = g1 ? (g0 ? l[0] : e) : l[1];
    l[0] = g0 ? e : l[0];
}

// descending (key,val) insert, depth N, SIGNED keys, fully unrolled
template<int N>
__device__ __forceinline__ void pins(int (&ks)[N], int (&vs)[N], int k, int v) {
    if (k <= ks[N-1]) return;
    #pragma unroll
    for (int p = N-1; p >= 0; --p) {
        bool gt  = k > ks[p];
        bool gtp = (p > 0) ? (k > ks[p-1]) : false;
        int nk = gt ? (gtp ? ks[p-1] : k) : ks[p];
        int nv = gt ? (gtp ? vs[p-1] : v) : vs[p];
        ks[p] = nk; vs[p] = nv;
    }
}

// ---------------------------------------------------------------------------
// Kernel 1: pack weight (and gathered query rows) into bf16 MFMA fragments,
// kb-OUTER layout (4 col-blocks per workgroup).  [unchanged from round 6]
// ---------------------------------------------------------------------------
__global__ __launch_bounds__(256)
void convert_frags(const int* __restrict__ wordid, const float* __restrict__ weight,
                   ushort* __restrict__ ws_b, ushort* __restrict__ ws_a, int nb4)
{
    __shared__ float Raw[16][324];
    __shared__ int   Rows[16];

    const int bid = blockIdx.x;
    const int t   = threadIdx.x;
    const bool is_a = (bid >= nb4);
    const int cb0 = (is_a ? (bid - nb4) : bid) * 4;
    ushort* dst = is_a ? ws_a : ws_b;
    const int kstride = is_a ? 64 : NCB_B;

    for (int sub = 0; sub < 4; ++sub) {
        const int cb = cb0 + sub;
        __syncthreads();                      // protect Raw from prev iter readers
        if (t < 16) {
            int gr = is_a ? wordid[cb*16 + t] : (cb*16 + t);
            Rows[t] = (gr < VOCAB) ? gr : -1;
        }
        __syncthreads();
        for (int idx = t; idx < 16*80; idx += 256) {
            int row = idx / 80;
            int f4  = idx - row*80;
            int gr  = Rows[row];
            float4 v = make_float4(0.f,0.f,0.f,0.f);
            if (gr >= 0 && f4 < 75)
                v = *reinterpret_cast<const float4*>(&weight[(size_t)gr*KDIM + f4*4]);
            *reinterpret_cast<float4*>(&Raw[row][f4*4]) = v;
        }
        __syncthreads();
        for (int idx = t; idx < NKB*64; idx += 256) {
            int kb   = idx >> 6;
            int lane = idx & 63;
            int r16  = lane & 15;
            int k0   = kb*32 + (lane>>4)*8;
            unsigned p[4];
            #pragma unroll
            for (int q = 0; q < 4; ++q) {
                unsigned lo = f2bf(Raw[r16][k0 + 2*q]);
                unsigned hi = f2bf(Raw[r16][k0 + 2*q + 1]);
                p[q] = lo | (hi << 16);
            }
            *reinterpret_cast<uint4*>(&dst[((size_t)kb*kstride + cb)*512 + (size_t)lane*8]) =
                make_uint4(p[0], p[1], p[2], p[3]);
        }
    }
}

// ---------------------------------------------------------------------------
// Kernel 2: counted-vmcnt 3-buffer MFMA pipeline + fused quad-max candidates.
// Round 8: flat grid of NCHPAD*8 blocks with XCD-residency swizzle —
//   id = (chunk%8) + 8*(rowblock + 8*(chunk/8))   (bijective on [0,832))
// so all 8 rowblock-blocks sharing one chunk's 640 KB B panel have
// id % 8 == chunk % 8 -> same XCD under round-robin dispatch -> the panel
// is pulled into exactly one L2 instead of eight.
// ---------------------------------------------------------------------------
__global__ __launch_bounds__(256, 3)
void sim_gemm(const ushort* __restrict__ ws_a, const ushort* __restrict__ ws_b,
              unsigned* __restrict__ cand)
{
    __shared__ __align__(16) ushort Abuf[3][8*512];
    __shared__ __align__(16) ushort Bbuf[3][8*512];

    const int id    = blockIdx.x;
    const int chunk = (id & 7) + ((id >> 6) << 3);   // residue + 8*(id/64)
    const int rbid  = (id >> 3) & 7;                 // rowblock 0..7
    if (chunk >= NCHUNK) return;

    const int t     = threadIdx.x;
    const int wid   = t >> 6, lane = t & 63;
    const int wm    = wid >> 1, wn = wid & 1;
    const int l16   = lane & 15, lk = lane >> 4;
    const int rb16b = rbid * 8;

    int ps[4][4];
    #pragma unroll
    for (int m = 0; m < 4; ++m)
        #pragma unroll
        for (int e = 0; e < 4; ++e) ps[m][e] = 0;

    const int f = wid * 2;
    const ushort* abase = ws_a + ((size_t)(rb16b + f)*512) + (size_t)lane*8;
    const ushort* bbase = ws_b + ((size_t)(chunk*64 + f)*512) + (size_t)lane*8;

    auto stage = [&](int sit, int skb, int buf) {
        const ushort* pa = abase + (size_t)skb*(64*512);
        GL2LDS(pa,       &Abuf[buf][f*512]);
        GL2LDS(pa + 512, &Abuf[buf][(f+1)*512]);
        const ushort* pb = bbase + (size_t)skb*((size_t)NCB_B*512) + (size_t)sit*(8*512);
        GL2LDS(pb,       &Bbuf[buf][f*512]);
        GL2LDS(pb + 512, &Bbuf[buf][(f+1)*512]);
    };

    stage(0, 0, 0);
    stage(0, 1, 1);
    int nit = 0, nkb = 2;
    int cur = 0;
    int s = 0;
    const int qbase = wn*16 + lk;

    for (int it = 0; it < NWIN; ++it) {
        f32x4 acc[4][4] = {};

        for (int kb = 0; kb < NKB; ++kb, ++s) {
            if (s == NSTEP-1) { asm volatile("s_waitcnt vmcnt(0)" ::: "memory"); }
            else              { asm volatile("s_waitcnt vmcnt(4)" ::: "memory"); }
            __builtin_amdgcn_s_barrier();
            asm volatile("" ::: "memory");

            bf16x8 af[4], bfr[4];
            #pragma unroll
            for (int m = 0; m < 4; ++m)
                af[m] = *reinterpret_cast<const bf16x8*>(&Abuf[cur][(wm*4+m)*512 + lane*8]);
            #pragma unroll
            for (int n = 0; n < 4; ++n)
                bfr[n] = *reinterpret_cast<const bf16x8*>(&Bbuf[cur][(wn*4+n)*512 + lane*8]);

            if (s < NSTEP-2) {
                int nxt = cur - 1; if (nxt < 0) nxt = 2;
                stage(nit, nkb, nxt);
                ++nkb; if (nkb == NKB) { nkb = 0; ++nit; }
            }

            #pragma unroll
            for (int m = 0; m < 4; ++m)
                #pragma unroll
                for (int n = 0; n < 4; ++n)
                    acc[m][n] = __builtin_amdgcn_mfma_f32_16x16x32_bf16(bfr[n], af[m], acc[m][n], 0, 0, 0);

            ++cur; if (cur == 3) cur = 0;
        }

        #pragma unroll
        for (int m = 0; m < 4; ++m)
            #pragma unroll
            for (int n = 0; n < 4; ++n) {
                float qm = fmaxf(fmaxf(acc[m][n][0], acc[m][n][1]),
                                 fmaxf(acc[m][n][2], acc[m][n][3]));
                int key = (int)((__float_as_uint(qm) & 0xFFFF0000u)
                                | (unsigned)(it*32 + n*4 + qbase));
                ins4(ps[m], key);
            }
    }

    #pragma unroll
    for (int m = 0; m < 4; ++m) {
        int row = rb16b*16 + wm*64 + m*16 + l16;
        size_t base = (size_t)row*NCAND + chunk*CSLOT + wn*16 + lk*4;
        *reinterpret_cast<uint4*>(&cand[base]) =
            make_uint4((unsigned)ps[m][0], (unsigned)ps[m][1],
                       (unsigned)ps[m][2], (unsigned)ps[m][3]);
    }
}

// ---------------------------------------------------------------------------
// Kernel 3a: per row, hierarchical merge 3136 quad candidates -> top-24 quads.
// [unchanged from round 7]
// ---------------------------------------------------------------------------
__global__ __launch_bounds__(128, 4)
void merge_topq(const unsigned* __restrict__ cand, int* __restrict__ quads)
{
    __shared__ int Ks[128*8];
    __shared__ int Vs[128*8];
    __shared__ int K24[16*NKF];
    __shared__ int V24[16*NKF];

    const int row  = blockIdx.x;
    const int lane = threadIdx.x;

    int ks[8]; int vs[8];
    #pragma unroll
    for (int i = 0; i < 8; ++i) { ks[i] = 0; vs[i] = 0; }

    const unsigned* rc = cand + (size_t)row*NCAND;
    for (int c = lane; c < NCAND; c += 128) {
        int e  = (int)rc[c];
        int gq = ((c >> 5) << 8) | (e & 255);   // chunk*256 + local quad
        pins<8>(ks, vs, e, gq);
    }
    #pragma unroll
    for (int i = 0; i < 8; ++i) { Ks[lane*8 + i] = ks[i]; Vs[lane*8 + i] = vs[i]; }
    __syncthreads();

    if (lane < 16) {
        int gk[NKF]; int gv[NKF];
        #pragma unroll
        for (int i = 0; i < NKF; ++i) { gk[i] = 0; gv[i] = 0; }
        for (int l = lane*8; l < lane*8 + 8; ++l) {
            for (int i = 0; i < 8; ++i) {          // lane lists sorted desc
                int e = Ks[l*8 + i];
                if (e <= gk[NKF-1]) break;
                pins<NKF>(gk, gv, e, Vs[l*8 + i]);
            }
        }
        #pragma unroll
        for (int i = 0; i < NKF; ++i) { K24[lane*NKF + i] = gk[i]; V24[lane*NKF + i] = gv[i]; }
    }
    __syncthreads();

    if (lane == 0) {
        int gk[NKF]; int gv[NKF];
        #pragma unroll
        for (int i = 0; i < NKF; ++i) { gk[i] = 0; gv[i] = 0; }
        for (int l = 0; l < 16; ++l) {
            for (int i = 0; i < NKF; ++i) {
                int e = K24[l*NKF + i];
                if (e <= gk[NKF-1]) break;
                pins<NKF>(gk, gv, e, V24[l*NKF + i]);
            }
        }
        #pragma unroll
        for (int i = 0; i < NKF; ++i) quads[row*NKF + i] = gv[i];
    }
}

// ---------------------------------------------------------------------------
// Kernel 3b: dense exact rescore. One 16-lane group per dot; 98304 dots.
// [unchanged from round 7]
// ---------------------------------------------------------------------------
__global__ __launch_bounds__(256, 8)
void rescore_exact(const int* __restrict__ quads, const int* __restrict__ wordid,
                   const float* __restrict__ weight, double* __restrict__ scores)
{
    const int g = (blockIdx.x * 256 + threadIdx.x) >> 4;   // dot id
    const int l = threadIdx.x & 15;
    const int row = g / NDOT;
    const int ci  = g - row * NDOT;

    const int q   = quads[row*NKF + (ci >> 2)];
    const int col = q*4 + (ci & 3);
    const bool valid = (col < VOCAB);
    const int col_eff = valid ? col : 0;

    const float* qr = weight + (size_t)wordid[row]*KDIM;
    const float* wr = weight + (size_t)col_eff*KDIM;

    double a0 = 0.0, a1 = 0.0;
    #pragma unroll
    for (int k = 0; k < 4; ++k) {
        int sl = (l + 16*k) * 4;
        float4 qa = *reinterpret_cast<const float4*>(qr + sl);
        float4 wb = *reinterpret_cast<const float4*>(wr + sl);
        a0 += (double)qa.x * wb.x + (double)qa.z * wb.z;
        a1 += (double)qa.y * wb.y + (double)qa.w * wb.w;
    }
    if (l < 11) {
        int sl = (l + 64) * 4;
        float4 qa = *reinterpret_cast<const float4*>(qr + sl);
        float4 wb = *reinterpret_cast<const float4*>(wr + sl);
        a0 += (double)qa.x * wb.x + (double)qa.z * wb.z;
        a1 += (double)qa.y * wb.y + (double)qa.w * wb.w;
    }
    double a = a0 + a1;
    #pragma unroll
    for (int m = 1; m < 16; m <<= 1) a += __shfl_xor(a, m);

    if (l == 0) scores[g] = valid ? a : -1e300;
}

// ---------------------------------------------------------------------------
// Kernel 3c: per row, wave-parallel top-11 of the 96 exact scores.
// [unchanged from round 7]
// ---------------------------------------------------------------------------
__global__ __launch_bounds__(64, 8)
void final_select(const double* __restrict__ scores, const int* __restrict__ quads,
                  float* __restrict__ out)
{
    const int row  = blockIdx.x;
    const int lane = threadIdx.x;

    double v0 = -INFINITY, v1 = -INFINITY;
    int    c0 = 0x7fffffff, c1 = 0x7fffffff;
    if (lane < NDOT/2) {
        int i0 = lane*2, i1 = lane*2 + 1;
        v0 = scores[(size_t)row*NDOT + i0];
        v1 = scores[(size_t)row*NDOT + i1];
        c0 = quads[row*NKF + (i0 >> 2)]*4 + (i0 & 3);
        c1 = quads[row*NKF + (i1 >> 2)]*4 + (i1 & 3);
    }

    for (int kk = 0; kk < TOPK + 1; ++kk) {
        bool sel = (v0 > v1) || (v0 == v1 && c0 < c1);
        double bv = sel ? v0 : v1;
        int    bc = sel ? c0 : c1;
        #pragma unroll
        for (int m = 1; m < 64; m <<= 1) {
            double ov = __shfl_xor(bv, m);
            int    oc = __shfl_xor(bc, m);
            if (ov > bv || (ov == bv && oc < bc)) { bv = ov; bc = oc; }
        }
        if (kk >= 1 && lane == 0) {
            out[(size_t)row*TOPK + (kk-1)] = (float)bv;
            out[(size_t)BATCH*TOPK + (size_t)row*TOPK + (kk-1)] = (float)bc;
        }
        if (c0 == bc) v0 = -INFINITY;
        if (c1 == bc) v1 = -INFINITY;
    }
}

extern "C" void kernel_launch(void* const* d_in, const int* in_sizes, int n_in,
                              void* d_out, int out_size, void* d_ws, size_t ws_size,
                              hipStream_t stream) {
    const int*   wordid = (const int*)d_in[0];
    const float* weight = (const float*)d_in[1];
    float* out = (float*)d_out;

    const size_t SZ_B = (size_t)NCB_B * NKB * 64 * 16;   // 64,225,280 B
    const size_t SZ_A = (size_t)NCB_A * NKB * 64 * 16;   //    655,360 B

    char* p = (char*)d_ws;
    ushort*   ws_b = (ushort*)p;  p += SZ_B;
    ushort*   ws_a = (ushort*)p;  p += SZ_A;
    unsigned* cand = (unsigned*)p;

    int*    quads  = (int*)ws_a;      // ws_a dead after sim_gemm
    double* scores = (double*)cand;   // cand dead after merge_topq

    convert_frags<<<NCB_B/4 + NCB_A/4, 256, 0, stream>>>(wordid, weight, ws_b, ws_a, NCB_B/4);
    sim_gemm<<<NCHPAD*8, 256, 0, stream>>>(ws_a, ws_b, cand);
    merge_topq<<<BATCH, 128, 0, stream>>>(cand, quads);
    rescore_exact<<<(BATCH*NDOT)/16, 256, 0, stream>>>(quads, wordid, weight, scores);
    final_select<<<BATCH, 64, 0, stream>>>(scores, quads, out);
}